// Round 4
// baseline (185.568 us; speedup 1.0000x reference)
//
#include <hip/hip_runtime.h>

#define L_SEQ   4096
#define BATCH   2
#define DMODEL  1024
#define HEADS   16
#define DKH     64
#define NBF     16
#define CHUNK   64
#define NCHUNK  64          // L_SEQ / CHUNK
#define NCHAIN  32          // BATCH * HEADS
#define STATE_SZ 1040       // NBF*DKH + NBF
#define EPSF    1e-6f

typedef __attribute__((ext_vector_type(8))) __bf16 bf16x8;
typedef __attribute__((ext_vector_type(4))) float  floatx4;

__device__ __forceinline__ unsigned short f2bf(float x) {
  unsigned u = __builtin_bit_cast(unsigned, x);
  u += 0x7fffu + ((u >> 16) & 1u);
  return (unsigned short)(u >> 16);
}
__device__ __forceinline__ float bf2f(unsigned short u) {
  return __builtin_bit_cast(float, ((unsigned)u) << 16);
}

#define GLOAD16(gp, lp) \
  __builtin_amdgcn_global_load_lds((const __attribute__((address_space(1))) void*)(gp), \
                                   (__attribute__((address_space(3))) void*)(lp), 16, 0, 0)

// ---------------- cast f32 -> bf16 (weights wv, wo) ----------------
__global__ __launch_bounds__(256) void cast2(const float* __restrict__ a, const float* __restrict__ b,
                                             unsigned short* __restrict__ oa, unsigned short* __restrict__ ob,
                                             int n4) {
  int i = blockIdx.x * 256 + threadIdx.x;
  if (i >= n4) return;
  const float* in = blockIdx.y ? b : a;
  unsigned short* out = blockIdx.y ? ob : oa;
  float4 v = ((const float4*)in)[i];
  ushort4 o;
  o.x = f2bf(v.x); o.y = f2bf(v.y); o.z = f2bf(v.z); o.w = f2bf(v.w);
  ((ushort4*)out)[i] = o;
}

// ---------------- combine: Wt[h*16+f, :] = sum_d omega[f,d] * w[h*64+d, :] (bf16 out) ----------------
__global__ __launch_bounds__(256) void combine_w(const float* __restrict__ wq, const float* __restrict__ wk,
                                                 const float* __restrict__ omega,
                                                 unsigned short* __restrict__ wtq,
                                                 unsigned short* __restrict__ wtk) {
  const int s = blockIdx.x;   // 64-col slab
  const int h = blockIdx.y;   // head
  const float* w = blockIdx.z ? wk : wq;
  unsigned short* wt = blockIdx.z ? wtk : wtq;
  __shared__ float ws[64 * 64];
  __shared__ float oms[NBF * 64];
  const int tid = threadIdx.x;
  for (int i = tid; i < 64 * 64; i += 256) {
    int r = i >> 6, c = i & 63;
    ws[i] = w[(size_t)(h * 64 + r) * DMODEL + s * 64 + c];
  }
  for (int i = tid; i < NBF * 64; i += 256) oms[i] = omega[i];
  __syncthreads();
  for (int j = tid; j < NBF * 64; j += 256) {
    int f = j >> 6, c = j & 63;
    float acc = 0.f;
#pragma unroll
    for (int d = 0; d < 64; ++d) acc += oms[f * 64 + d] * ws[d * 64 + c];
    wt[(size_t)(h * NBF + f) * DMODEL + s * 64 + c] = f2bf(acc);
  }
}

// ---------------- GEMM with f32 A-operand (cast fused into staging), double-buffered ----------------
// C = A(MxK f32, cvt->bf16) * Bt(NxK bf16)^T
// FEAT=true : N=256 (Wt), epilogue = in-register feature map -> xp_t (f32)
// FEAT=false: N=1024, epilogue = bf16 C store
template <bool FEAT>
__global__ __launch_bounds__(256) void gemm_f32a(const float* __restrict__ Aq, const float* __restrict__ Ak,
                                                 const unsigned short* __restrict__ Bq,
                                                 const unsigned short* __restrict__ Bk,
                                                 float* __restrict__ outq, float* __restrict__ outk,
                                                 unsigned short* __restrict__ cout) {
  constexpr int K = DMODEL, NT = K / 32;
  __shared__ unsigned short As[2][128 * 32];
  __shared__ unsigned short Bs[2][128 * 32];
  const int tid  = threadIdx.x;
  const int wave = tid >> 6, lane = tid & 63;
  const int mt = blockIdx.y << 7, nt = blockIdx.x << 7;
  const int wm = (wave >> 1) << 6, wn = (wave & 1) << 6;
  const int r16 = lane & 15, kg = lane >> 4;

  const float* A = blockIdx.z ? Ak : Aq;
  const unsigned short* Bt = blockIdx.z ? Bk : Bq;

  floatx4 acc[4][4];
#pragma unroll
  for (int m = 0; m < 4; ++m)
#pragma unroll
    for (int n = 0; n < 4; ++n) acc[m][n] = floatx4{0.f, 0.f, 0.f, 0.f};

  // A staging map: thread covers rows ar0+32j (j=0..3), cols acol..acol+3 (f32)
  const int ar0  = tid >> 3;
  const int acol = (tid & 7) << 2;
  const float* aG = A + (size_t)(mt + ar0) * K + acol;
  // B staging map (16B bf16 per lane via global_load_lds)
  const int ldrow = wave * 16 + (lane >> 2);
  const int ldcol = (lane & 3) << 3;
  const unsigned short* bG = Bt + (size_t)(nt + ldrow) * K + ldcol;

  float4 rE[4], rO[4];

  auto loadA = [&](float4* r, int kt) {
#pragma unroll
    for (int j = 0; j < 4; ++j) r[j] = *(const float4*)(aG + (size_t)32 * j * K + kt);
  };
  auto stageB = [&](int buf, int kt) {
    char* bL = (char*)Bs[buf] + wave * 1024;
    GLOAD16(bG + kt, bL);
    GLOAD16(bG + (size_t)64 * K + kt, bL + 4096);
  };
  auto writeA = [&](int buf, const float4* r) {
#pragma unroll
    for (int j = 0; j < 4; ++j) {
      ushort4 u;
      u.x = f2bf(r[j].x); u.y = f2bf(r[j].y); u.z = f2bf(r[j].z); u.w = f2bf(r[j].w);
      *(ushort4*)&As[buf][(ar0 + 32 * j) * 32 + acol] = u;
    }
  };
  auto mfmaStep = [&](int buf) {
    bf16x8 af[4], bfr[4];
#pragma unroll
    for (int m = 0; m < 4; ++m)
      af[m] = *(const bf16x8*)&As[buf][(wm + m * 16 + r16) * 32 + kg * 8];
#pragma unroll
    for (int n = 0; n < 4; ++n)
      bfr[n] = *(const bf16x8*)&Bs[buf][(wn + n * 16 + r16) * 32 + kg * 8];
#pragma unroll
    for (int m = 0; m < 4; ++m)
#pragma unroll
      for (int n = 0; n < 4; ++n)
        acc[m][n] = __builtin_amdgcn_mfma_f32_16x16x32_bf16(af[m], bfr[n], acc[m][n], 0, 0, 0);
  };

  loadA(rE, 0);
  stageB(0, 0);
  for (int t = 0; t < NT; t += 2) {
    writeA(0, rE);                 // compiler vmcnt-waits rE (drains B[0] too: needed)
    __syncthreads();
    if (t + 1 < NT) { loadA(rO, (t + 1) * 32); stageB(1, (t + 1) * 32); }
    mfmaStep(0);
    if (t + 1 < NT) {
      writeA(1, rO);
      __syncthreads();
      if (t + 2 < NT) { loadA(rE, (t + 2) * 32); stageB(0, (t + 2) * 32); }
      mfmaStep(1);
    }
  }

  if (FEAT) {
    // 16 features of one (row, head) live in lanes r16=0..15 for fixed (m,n,r)
    const int hbase = (nt + wn) >> 4;
#pragma unroll
    for (int m = 0; m < 4; ++m) {
#pragma unroll
      for (int n = 0; n < 4; ++n) {
        const int hglob = hbase + n;
#pragma unroll
        for (int r = 0; r < 4; ++r) {
          float x = acc[m][n][r];
          float p = __expf(-0.5f * x * x);
          float s = p;
          s += __shfl_xor(s, 1);
          s += __shfl_xor(s, 2);
          s += __shfl_xor(s, 4);
          s += __shfl_xor(s, 8);
          float o = p / (s + EPSF);
          const int row = mt + wm + m * 16 + kg * 4 + r;
          const int b = row >> 12, l = row & 4095;
          float* xp_t = blockIdx.z ? outk : outq;
          xp_t[(((size_t)(b * HEADS + hglob)) * L_SEQ + l) * NBF + r16] = o;
        }
      }
    }
  } else {
#pragma unroll
    for (int m = 0; m < 4; ++m) {
      const int row0 = mt + wm + m * 16 + kg * 4;
#pragma unroll
      for (int n = 0; n < 4; ++n) {
        const int col = nt + wn + n * 16 + r16;
#pragma unroll
        for (int r = 0; r < 4; ++r)
          cout[(size_t)(row0 + r) * DMODEL + col] = f2bf(acc[m][n][r]);
      }
    }
  }
}

// ---------------- bf16 MFMA GEMM (A,B bf16), double-buffered: C(f32) = A * Bt^T ----------------
__global__ __launch_bounds__(256) void gemm_bt_f32out(const unsigned short* __restrict__ A,
                                                      const unsigned short* __restrict__ Bt,
                                                      float* __restrict__ C) {
  constexpr int K = DMODEL, NT = K / 32;
  __shared__ unsigned short As[2][128 * 32];
  __shared__ unsigned short Bs[2][128 * 32];
  const int tid  = threadIdx.x;
  const int wave = tid >> 6, lane = tid & 63;
  const int mt = blockIdx.y << 7, nt = blockIdx.x << 7;
  const int wm = (wave >> 1) << 6, wn = (wave & 1) << 6;
  const int r16 = lane & 15, kg = lane >> 4;

  floatx4 acc[4][4];
#pragma unroll
  for (int m = 0; m < 4; ++m)
#pragma unroll
    for (int n = 0; n < 4; ++n) acc[m][n] = floatx4{0.f, 0.f, 0.f, 0.f};

  const int ldrow = wave * 16 + (lane >> 2);
  const int ldcol = (lane & 3) << 3;
  const unsigned short* aG = A  + (size_t)(mt + ldrow) * K + ldcol;
  const unsigned short* bG = Bt + (size_t)(nt + ldrow) * K + ldcol;

  auto stage = [&](int buf, int kt) {
    char* aL = (char*)As[buf] + wave * 1024;
    char* bL = (char*)Bs[buf] + wave * 1024;
    GLOAD16(aG + kt, aL);
    GLOAD16(aG + (size_t)64 * K + kt, aL + 4096);
    GLOAD16(bG + kt, bL);
    GLOAD16(bG + (size_t)64 * K + kt, bL + 4096);
  };

  stage(0, 0);
  __syncthreads();
  for (int t = 0; t < NT; ++t) {
    if (t + 1 < NT) stage((t + 1) & 1, (t + 1) * 32);
    const int buf = t & 1;
    bf16x8 af[4], bfr[4];
#pragma unroll
    for (int m = 0; m < 4; ++m)
      af[m] = *(const bf16x8*)&As[buf][(wm + m * 16 + r16) * 32 + kg * 8];
#pragma unroll
    for (int n = 0; n < 4; ++n)
      bfr[n] = *(const bf16x8*)&Bs[buf][(wn + n * 16 + r16) * 32 + kg * 8];
#pragma unroll
    for (int m = 0; m < 4; ++m)
#pragma unroll
      for (int n = 0; n < 4; ++n)
        acc[m][n] = __builtin_amdgcn_mfma_f32_16x16x32_bf16(af[m], bfr[n], acc[m][n], 0, 0, 0);
    __syncthreads();
  }

#pragma unroll
  for (int m = 0; m < 4; ++m) {
    const int row0 = mt + wm + m * 16 + kg * 4;
#pragma unroll
    for (int n = 0; n < 4; ++n) {
      const int col = nt + wn + n * 16 + r16;
#pragma unroll
      for (int r = 0; r < 4; ++r)
        C[(size_t)(row0 + r) * DMODEL + col] = acc[m][n][r];
    }
  }
}

// ---------------- scan phase A: per-chunk local sums ----------------
__global__ __launch_bounds__(64) void scan_chunk_sum(const float* __restrict__ kp_t,
                                                     const unsigned short* __restrict__ vh,
                                                     float* __restrict__ Sws) {
  const int c = blockIdx.x & (NCHUNK - 1);
  const int chain = blockIdx.x >> 6;
  const int b = chain >> 4, h = chain & 15;
  const int d = threadIdx.x;
  __shared__ float kp_s[CHUNK * NBF];
  const float* kpB = kp_t + ((size_t)chain * L_SEQ + c * CHUNK) * NBF;
  for (int i = 0; i < 16; ++i) kp_s[d + i * 64] = kpB[d + i * 64];
  __syncthreads();
  float S[NBF];
#pragma unroll
  for (int f = 0; f < NBF; ++f) S[f] = 0.f;
  const unsigned short* vB = vh + ((size_t)(b * L_SEQ + c * CHUNK)) * DMODEL + h * DKH + d;
  for (int l = 0; l < CHUNK; ++l) {
    float vv = bf2f(vB[(size_t)l * DMODEL]);
#pragma unroll
    for (int f = 0; f < NBF; ++f) S[f] += kp_s[l * NBF + f] * vv;
  }
  float* out = Sws + ((size_t)chain * NCHUNK + c) * STATE_SZ;
#pragma unroll
  for (int f = 0; f < NBF; ++f) out[f * 64 + d] = S[f];
  if (d < NBF) {
    float ks = 0.f;
    for (int l = 0; l < CHUNK; ++l) ks += kp_s[l * NBF + d];
    out[1024 + d] = ks;
  }
}

// ---------------- scan phase B: exclusive scan over chunks (parallel over e) ----------------
__global__ __launch_bounds__(64) void scan_chunks(float* __restrict__ Sws) {
  const int chain = blockIdx.x;
  const int e = blockIdx.y * 64 + threadIdx.x;
  if (e >= STATE_SZ) return;
  float acc = 0.f;
  float* p = Sws + (size_t)chain * NCHUNK * STATE_SZ + e;
  for (int c = 0; c < NCHUNK; ++c) {
    float v = p[(size_t)c * STATE_SZ];
    p[(size_t)c * STATE_SZ] = acc;
    acc += v;
  }
}

// ---------------- scan phase C: apply within chunk, write attn (bf16) ----------------
__global__ __launch_bounds__(64) void scan_apply(const float* __restrict__ qp_t,
                                                 const float* __restrict__ kp_t,
                                                 const unsigned short* __restrict__ vh,
                                                 const float* __restrict__ Sws,
                                                 unsigned short* __restrict__ attn) {
  const int c = blockIdx.x & (NCHUNK - 1);
  const int chain = blockIdx.x >> 6;
  const int b = chain >> 4, h = chain & 15;
  const int d = threadIdx.x;
  __shared__ float kp_s[CHUNK * NBF];
  __shared__ float qp_s[CHUNK * NBF];
  {
    const float* kpB = kp_t + ((size_t)chain * L_SEQ + c * CHUNK) * NBF;
    const float* qpB = qp_t + ((size_t)chain * L_SEQ + c * CHUNK) * NBF;
    for (int i = 0; i < 16; ++i) {
      kp_s[d + i * 64] = kpB[d + i * 64];
      qp_s[d + i * 64] = qpB[d + i * 64];
    }
  }
  __syncthreads();
  const float* st = Sws + ((size_t)chain * NCHUNK + c) * STATE_SZ;
  float S[NBF], kc[NBF];
#pragma unroll
  for (int f = 0; f < NBF; ++f) S[f] = st[f * 64 + d];
#pragma unroll
  for (int f = 0; f < NBF; ++f) kc[f] = st[1024 + f];
  const unsigned short* vB = vh + ((size_t)(b * L_SEQ + c * CHUNK)) * DMODEL + h * DKH + d;
  unsigned short* oB = attn + ((size_t)(b * L_SEQ + c * CHUNK)) * DMODEL + h * DKH + d;
  for (int l = 0; l < CHUNK; ++l) {
    float vv = bf2f(vB[(size_t)l * DMODEL]);
    float num = 0.f, den = 0.f;
#pragma unroll
    for (int f = 0; f < NBF; ++f) {
      float kpf = kp_s[l * NBF + f];
      S[f]  += kpf * vv;
      kc[f] += kpf;
      float qpf = qp_s[l * NBF + f];
      num += qpf * S[f];
      den += qpf * kc[f];
    }
    oB[(size_t)l * DMODEL] = f2bf(num / (den + EPSF));
  }
}

// ---------------- host launch ----------------
extern "C" void kernel_launch(void* const* d_in, const int* in_sizes, int n_in,
                              void* d_out, int out_size, void* d_ws, size_t ws_size,
                              hipStream_t stream) {
  const float* q   = (const float*)d_in[0];
  const float* k   = (const float*)d_in[1];
  const float* v   = (const float*)d_in[2];
  const float* w_q = (const float*)d_in[3];
  const float* w_k = (const float*)d_in[4];
  const float* w_v = (const float*)d_in[5];
  const float* w_o = (const float*)d_in[6];
  const float* omega = (const float*)d_in[7];
  float* out = (float*)d_out;

  constexpr size_t NQ = (size_t)BATCH * L_SEQ * DMODEL;      // 8388608
  constexpr size_t NW = (size_t)DMODEL * DMODEL;             // 1048576
  constexpr size_t NWT = (size_t)HEADS * NBF * DMODEL;       // 262144
  constexpr size_t NP = (size_t)BATCH * HEADS * L_SEQ * NBF; // 2097152
  constexpr size_t NS = (size_t)NCHAIN * NCHUNK * STATE_SZ;

  char* ws = (char*)d_ws;
  size_t off = 0;
  auto alc = [&](size_t bytes) { void* p = ws + off; off += (bytes + 255) & ~(size_t)255; return p; };
  unsigned short* wvb = (unsigned short*)alc(NW * 2);
  unsigned short* wob = (unsigned short*)alc(NW * 2);
  unsigned short* wtq = (unsigned short*)alc(NWT * 2);
  unsigned short* wtk = (unsigned short*)alc(NWT * 2);
  unsigned short* vh  = (unsigned short*)alc(NQ * 2);
  unsigned short* attn = (unsigned short*)alc(NQ * 2);
  float* qp  = (float*)alc(NP * 4);
  float* kp  = (float*)alc(NP * 4);
  float* Sws = (float*)alc(NS * 4);

  combine_w<<<dim3(16, 16, 2), 256, 0, stream>>>(w_q, w_k, omega, wtq, wtk);
  cast2<<<dim3((int)(NW / 4 / 256), 2), 256, 0, stream>>>(w_v, w_o, wvb, wob, (int)(NW / 4));

  // q,k projections (N=256) + fused feature map; f32 A staged in-kernel
  gemm_f32a<true><<<dim3(2, 64, 2), 256, 0, stream>>>(q, k, wtq, wtk, qp, kp, nullptr);
  // v projection (N=1024); f32 A staged in-kernel
  gemm_f32a<false><<<dim3(8, 64, 1), 256, 0, stream>>>(v, v, wvb, wvb, nullptr, nullptr, vh);

  scan_chunk_sum<<<NCHAIN * NCHUNK, 64, 0, stream>>>(kp, vh, Sws);
  scan_chunks<<<dim3(NCHAIN, (STATE_SZ + 63) / 64), 64, 0, stream>>>(Sws);
  scan_apply<<<NCHAIN * NCHUNK, 64, 0, stream>>>(qp, kp, vh, Sws, attn);

  gemm_bt_f32out<<<dim3(8, 64), 256, 0, stream>>>(attn, wob, out);
}

// Round 5
// 169.590 us; speedup vs baseline: 1.0942x; 1.0942x over previous
//
#include <hip/hip_runtime.h>

#define L_SEQ   4096
#define BATCH   2
#define DMODEL  1024
#define HEADS   16
#define DKH     64
#define NBF     16
#define CHUNK   64
#define NCHUNK  64          // L_SEQ / CHUNK
#define NCHAIN  32          // BATCH * HEADS
#define STATE_SZ 1040       // NBF*DKH + NBF
#define EPSF    1e-6f

typedef __attribute__((ext_vector_type(8))) __bf16 bf16x8;
typedef __attribute__((ext_vector_type(4))) float  floatx4;

__device__ __forceinline__ unsigned short f2bf(float x) {
  unsigned u = __builtin_bit_cast(unsigned, x);
  u += 0x7fffu + ((u >> 16) & 1u);
  return (unsigned short)(u >> 16);
}
__device__ __forceinline__ float bf2f(unsigned short u) {
  return __builtin_bit_cast(float, ((unsigned)u) << 16);
}

#define GLOAD16(gp, lp) \
  __builtin_amdgcn_global_load_lds((const __attribute__((address_space(1))) void*)(gp), \
                                   (__attribute__((address_space(3))) void*)(lp), 16, 0, 0)
#define WAIT_V4L0()  asm volatile("s_waitcnt vmcnt(4) lgkmcnt(0)" ::: "memory")
#define WAIT_V0L0()  asm volatile("s_waitcnt vmcnt(0) lgkmcnt(0)" ::: "memory")
#define SBAR()       __builtin_amdgcn_s_barrier()
#define SCHED0()     __builtin_amdgcn_sched_barrier(0)

// ---------------- prep: cast wv,wo to bf16 + combine wtq,wtk ----------------
// blocks 0..1023: wv cast; 1024..2047: wo cast; 2048..2559: combine (z,h,s)
__global__ __launch_bounds__(256) void prep(const float* __restrict__ wv, const float* __restrict__ wo,
                                            const float* __restrict__ wq, const float* __restrict__ wk,
                                            const float* __restrict__ omega,
                                            unsigned short* __restrict__ wvb, unsigned short* __restrict__ wob,
                                            unsigned short* __restrict__ wtq, unsigned short* __restrict__ wtk) {
  __shared__ float ws[64 * 64];
  __shared__ float oms[NBF * 64];
  const int blk = blockIdx.x;
  const int tid = threadIdx.x;
  if (blk < 2048) {
    const float* in = (blk < 1024) ? wv : wo;
    unsigned short* out = (blk < 1024) ? wvb : wob;
    int i = (blk & 1023) * 256 + tid;   // 1024*256 == NW/4 exactly
    float4 v4 = ((const float4*)in)[i];
    ushort4 o;
    o.x = f2bf(v4.x); o.y = f2bf(v4.y); o.z = f2bf(v4.z); o.w = f2bf(v4.w);
    ((ushort4*)out)[i] = o;
    return;
  }
  const int local = blk - 2048;          // 0..511
  const int z = local >> 8;              // 0:q 1:k
  const int h = (local & 255) >> 4;
  const int s = local & 15;              // 64-col slab
  const float* w = z ? wk : wq;
  unsigned short* wt = z ? wtk : wtq;
  for (int i = tid; i < 64 * 64; i += 256) {
    int r = i >> 6, c = i & 63;
    ws[i] = w[(size_t)(h * 64 + r) * DMODEL + s * 64 + c];
  }
  for (int i = tid; i < NBF * 64; i += 256) oms[i] = omega[i];
  __syncthreads();
  for (int j = tid; j < NBF * 64; j += 256) {
    int f = j >> 6, c = j & 63;
    float acc = 0.f;
#pragma unroll
    for (int d = 0; d < 64; ++d) acc += oms[f * 64 + d] * ws[d * 64 + c];
    wt[(size_t)(h * NBF + f) * DMODEL + s * 64 + c] = f2bf(acc);
  }
}

// ---------------- fused projections: q-feat (128 wgs) | k-feat (128) | v (512) ----------------
// 1D grid 768 blocks, XCD-swizzled. A is f32 (cast fused into reg-staged A path).
// Counted-vmcnt single-barrier-per-K-step pipeline (T3/T4-lite).
__global__ __launch_bounds__(256) void proj_all(const float* __restrict__ q, const float* __restrict__ k,
                                                const float* __restrict__ v,
                                                const unsigned short* __restrict__ wtq,
                                                const unsigned short* __restrict__ wtk,
                                                const unsigned short* __restrict__ wvb,
                                                float* __restrict__ qp_t, float* __restrict__ kp_t,
                                                unsigned short* __restrict__ vh) {
  constexpr int K = DMODEL, NT = K / 32;
  __shared__ unsigned short As[2][128 * 32];
  __shared__ unsigned short Bs[2][128 * 32];
  const int tid  = threadIdx.x;
  const int wave = tid >> 6, lane = tid & 63;

  const int bid = blockIdx.x;
  const int id = (bid & 7) * 96 + (bid >> 3);   // bijective XCD swizzle, 768 wgs
  int op, mt, nt;
  const float* A;
  const unsigned short* Bt;
  if (id < 256) {            // q/k projection, N=256
    op = id >> 7;            // 0:q 1:k
    const int local = id & 127;
    nt = (local & 1) << 7;
    mt = (local >> 1) << 7;
    A  = op ? k : q;
    Bt = op ? wtk : wtq;
  } else {                   // v projection, N=1024
    op = 2;
    const int local = id - 256;
    nt = (local & 7) << 7;
    mt = (local >> 3) << 7;
    A  = v;
    Bt = wvb;
  }

  const int wm = (wave >> 1) << 6, wn = (wave & 1) << 6;
  const int r16 = lane & 15, kg = lane >> 4;

  floatx4 acc[4][4];
#pragma unroll
  for (int m = 0; m < 4; ++m)
#pragma unroll
    for (int n = 0; n < 4; ++n) acc[m][n] = floatx4{0.f, 0.f, 0.f, 0.f};

  // A staging map: thread covers rows ar0+32j (j=0..3), 4 f32 cols at acol
  const int ar0  = tid >> 3;
  const int acol = (tid & 7) << 2;
  const float* aG = A + (size_t)(mt + ar0) * K + acol;
  // B staging map: 16B bf16 per lane via global_load_lds, linear LDS
  const int ldrow = wave * 16 + (lane >> 2);
  const int ldcol = (lane & 3) << 3;
  const unsigned short* bG = Bt + (size_t)(nt + ldrow) * K + ldcol;

  float4 rA0[4], rA1[4];

  auto loadA = [&](float4* r, int kt) {
#pragma unroll
    for (int j = 0; j < 4; ++j) r[j] = *(const float4*)(aG + (size_t)32 * j * K + kt);
  };
  auto stageB = [&](int buf, int kt) {
    char* bL = (char*)Bs[buf] + wave * 1024;
    GLOAD16(bG + kt, bL);
    GLOAD16(bG + (size_t)64 * K + kt, bL + 4096);
  };
  auto writeA = [&](int buf, const float4* r) {
#pragma unroll
    for (int j = 0; j < 4; ++j) {
      ushort4 u;
      u.x = f2bf(r[j].x); u.y = f2bf(r[j].y); u.z = f2bf(r[j].z); u.w = f2bf(r[j].w);
      *(ushort4*)&As[buf][(ar0 + 32 * j) * 32 + acol] = u;
    }
  };
  auto mfmaStep = [&](int buf) {
    bf16x8 af[4], bfr[4];
#pragma unroll
    for (int m = 0; m < 4; ++m)
      af[m] = *(const bf16x8*)&As[buf][(wm + m * 16 + r16) * 32 + kg * 8];
#pragma unroll
    for (int n = 0; n < 4; ++n)
      bfr[n] = *(const bf16x8*)&Bs[buf][(wn + n * 16 + r16) * 32 + kg * 8];
#pragma unroll
    for (int m = 0; m < 4; ++m)
#pragma unroll
      for (int n = 0; n < 4; ++n)
        acc[m][n] = __builtin_amdgcn_mfma_f32_16x16x32_bf16(af[m], bfr[n], acc[m][n], 0, 0, 0);
  };

  // prologue: tile0 into buf0; tile1 regs in flight
  loadA(rA0, 0);
  stageB(0, 0);
  SCHED0();
  writeA(0, rA0);          // compiler vmcnt-waits rA0
  loadA(rA1, 32);
  WAIT_V4L0();             // Bs[0] landed (rA1 still flying); ds_writes done
  SCHED0();
  SBAR();

  for (int t = 0; t < NT; t += 2) {
    // ---- even iter: compute buf0 (tile t); stage tile t+1 -> buf1 ----
    if (t + 1 < NT) stageB(1, (t + 1) * 32);
    SCHED0();                              // pin stageB before loadA (vmcnt count)
    if (t + 1 < NT) writeA(1, rA1);        // rA1 = tile t+1 (issued at t-1)
    if (t + 2 < NT) loadA(rA0, (t + 2) * 32);
    mfmaStep(0);
    WAIT_V4L0();                           // retire stageB(t+1); loadA(t+2) keeps flying
    SCHED0();
    SBAR();
    // ---- odd iter: compute buf1 (tile t+1); stage tile t+2 -> buf0 ----
    if (t + 2 < NT) stageB(0, (t + 2) * 32);
    SCHED0();
    if (t + 2 < NT) writeA(0, rA0);
    if (t + 3 < NT) loadA(rA1, (t + 3) * 32);
    mfmaStep(1);
    WAIT_V4L0();
    SCHED0();
    SBAR();
  }

  if (op < 2) {
    // feature epilogue: 16 features of one (row, head) live in lanes r16=0..15
    float* xp_t = op ? kp_t : qp_t;
    const int hbase = (nt + wn) >> 4;
#pragma unroll
    for (int m = 0; m < 4; ++m) {
#pragma unroll
      for (int n = 0; n < 4; ++n) {
        const int hglob = hbase + n;
#pragma unroll
        for (int r = 0; r < 4; ++r) {
          float x = acc[m][n][r];
          float p = __expf(-0.5f * x * x);
          float s = p;
          s += __shfl_xor(s, 1);
          s += __shfl_xor(s, 2);
          s += __shfl_xor(s, 4);
          s += __shfl_xor(s, 8);
          float o = p / (s + EPSF);
          const int row = mt + wm + m * 16 + kg * 4 + r;
          const int b = row >> 12, l = row & 4095;
          xp_t[(((size_t)(b * HEADS + hglob)) * L_SEQ + l) * NBF + r16] = o;
        }
      }
    }
  } else {
#pragma unroll
    for (int m = 0; m < 4; ++m) {
      const int row0 = mt + wm + m * 16 + kg * 4;
#pragma unroll
      for (int n = 0; n < 4; ++n) {
        const int col = nt + wn + n * 16 + r16;
#pragma unroll
        for (int r = 0; r < 4; ++r)
          vh[(size_t)(row0 + r) * DMODEL + col] = f2bf(acc[m][n][r]);
      }
    }
  }
}

// ---------------- o-GEMM: out(f32) = attn(bf16) * wob^T, counted-vmcnt pipeline ----------------
__global__ __launch_bounds__(256) void gemm_o(const unsigned short* __restrict__ A,
                                              const unsigned short* __restrict__ Bt,
                                              float* __restrict__ C) {
  constexpr int K = DMODEL, NT = K / 32;
  __shared__ unsigned short As[2][128 * 32];
  __shared__ unsigned short Bs[2][128 * 32];
  const int tid  = threadIdx.x;
  const int wave = tid >> 6, lane = tid & 63;
  const int bid = blockIdx.x;
  const int id = (bid & 7) * 64 + (bid >> 3);   // bijective XCD swizzle, 512 wgs
  const int nt = (id & 7) << 7, mt = (id >> 3) << 7;
  const int wm = (wave >> 1) << 6, wn = (wave & 1) << 6;
  const int r16 = lane & 15, kg = lane >> 4;

  floatx4 acc[4][4];
#pragma unroll
  for (int m = 0; m < 4; ++m)
#pragma unroll
    for (int n = 0; n < 4; ++n) acc[m][n] = floatx4{0.f, 0.f, 0.f, 0.f};

  const int ldrow = wave * 16 + (lane >> 2);
  const int ldcol = (lane & 3) << 3;
  const unsigned short* aG = A  + (size_t)(mt + ldrow) * K + ldcol;
  const unsigned short* bG = Bt + (size_t)(nt + ldrow) * K + ldcol;

  auto stage = [&](int buf, int kt) {
    char* aL = (char*)As[buf] + wave * 1024;
    char* bL = (char*)Bs[buf] + wave * 1024;
    GLOAD16(aG + kt, aL);
    GLOAD16(aG + (size_t)64 * K + kt, aL + 4096);
    GLOAD16(bG + kt, bL);
    GLOAD16(bG + (size_t)64 * K + kt, bL + 4096);
  };

  stage(0, 0);
  WAIT_V0L0();
  SCHED0();
  SBAR();
  for (int t = 0; t < NT; ++t) {
    if (t + 1 < NT) stage((t + 1) & 1, (t + 1) * 32);   // issue next-tile loads FIRST
    const int buf = t & 1;
    bf16x8 af[4], bfr[4];
#pragma unroll
    for (int m = 0; m < 4; ++m)
      af[m] = *(const bf16x8*)&As[buf][(wm + m * 16 + r16) * 32 + kg * 8];
#pragma unroll
    for (int n = 0; n < 4; ++n)
      bfr[n] = *(const bf16x8*)&Bs[buf][(wn + n * 16 + r16) * 32 + kg * 8];
#pragma unroll
    for (int m = 0; m < 4; ++m)
#pragma unroll
      for (int n = 0; n < 4; ++n)
        acc[m][n] = __builtin_amdgcn_mfma_f32_16x16x32_bf16(af[m], bfr[n], acc[m][n], 0, 0, 0);
    WAIT_V0L0();            // next-tile stage landed (flew under ds_read+MFMA)
    SCHED0();
    SBAR();
  }

#pragma unroll
  for (int m = 0; m < 4; ++m) {
    const int row0 = mt + wm + m * 16 + kg * 4;
#pragma unroll
    for (int n = 0; n < 4; ++n) {
      const int col = nt + wn + n * 16 + r16;
#pragma unroll
      for (int r = 0; r < 4; ++r)
        C[(size_t)(row0 + r) * DMODEL + col] = acc[m][n][r];
    }
  }
}

// ---------------- scan phase A: per-chunk local sums ----------------
__global__ __launch_bounds__(64) void scan_chunk_sum(const float* __restrict__ kp_t,
                                                     const unsigned short* __restrict__ vh,
                                                     float* __restrict__ Sws) {
  const int c = blockIdx.x & (NCHUNK - 1);
  const int chain = blockIdx.x >> 6;
  const int b = chain >> 4, h = chain & 15;
  const int d = threadIdx.x;
  __shared__ float kp_s[CHUNK * NBF];
  const float* kpB = kp_t + ((size_t)chain * L_SEQ + c * CHUNK) * NBF;
  for (int i = 0; i < 16; ++i) kp_s[d + i * 64] = kpB[d + i * 64];
  __syncthreads();
  float S[NBF];
#pragma unroll
  for (int f = 0; f < NBF; ++f) S[f] = 0.f;
  const unsigned short* vB = vh + ((size_t)(b * L_SEQ + c * CHUNK)) * DMODEL + h * DKH + d;
  for (int l = 0; l < CHUNK; ++l) {
    float vv = bf2f(vB[(size_t)l * DMODEL]);
#pragma unroll
    for (int f = 0; f < NBF; ++f) S[f] += kp_s[l * NBF + f] * vv;
  }
  float* out = Sws + ((size_t)chain * NCHUNK + c) * STATE_SZ;
#pragma unroll
  for (int f = 0; f < NBF; ++f) out[f * 64 + d] = S[f];
  if (d < NBF) {
    float ks = 0.f;
    for (int l = 0; l < CHUNK; ++l) ks += kp_s[l * NBF + d];
    out[1024 + d] = ks;
  }
}

// ---------------- scan phase B: exclusive scan over chunks (parallel over e) ----------------
__global__ __launch_bounds__(64) void scan_chunks(float* __restrict__ Sws) {
  const int chain = blockIdx.x;
  const int e = blockIdx.y * 64 + threadIdx.x;
  if (e >= STATE_SZ) return;
  float acc = 0.f;
  float* p = Sws + (size_t)chain * NCHUNK * STATE_SZ + e;
  for (int c = 0; c < NCHUNK; ++c) {
    float v = p[(size_t)c * STATE_SZ];
    p[(size_t)c * STATE_SZ] = acc;
    acc += v;
  }
}

// ---------------- scan phase C: apply within chunk, write attn (bf16) ----------------
__global__ __launch_bounds__(64) void scan_apply(const float* __restrict__ qp_t,
                                                 const float* __restrict__ kp_t,
                                                 const unsigned short* __restrict__ vh,
                                                 const float* __restrict__ Sws,
                                                 unsigned short* __restrict__ attn) {
  const int c = blockIdx.x & (NCHUNK - 1);
  const int chain = blockIdx.x >> 6;
  const int b = chain >> 4, h = chain & 15;
  const int d = threadIdx.x;
  __shared__ float kp_s[CHUNK * NBF];
  __shared__ float qp_s[CHUNK * NBF];
  {
    const float* kpB = kp_t + ((size_t)chain * L_SEQ + c * CHUNK) * NBF;
    const float* qpB = qp_t + ((size_t)chain * L_SEQ + c * CHUNK) * NBF;
    for (int i = 0; i < 16; ++i) {
      kp_s[d + i * 64] = kpB[d + i * 64];
      qp_s[d + i * 64] = qpB[d + i * 64];
    }
  }
  __syncthreads();
  const float* st = Sws + ((size_t)chain * NCHUNK + c) * STATE_SZ;
  float S[NBF], kc[NBF];
#pragma unroll
  for (int f = 0; f < NBF; ++f) S[f] = st[f * 64 + d];
#pragma unroll
  for (int f = 0; f < NBF; ++f) kc[f] = st[1024 + f];
  const unsigned short* vB = vh + ((size_t)(b * L_SEQ + c * CHUNK)) * DMODEL + h * DKH + d;
  unsigned short* oB = attn + ((size_t)(b * L_SEQ + c * CHUNK)) * DMODEL + h * DKH + d;
  for (int l = 0; l < CHUNK; ++l) {
    float vv = bf2f(vB[(size_t)l * DMODEL]);
    float num = 0.f, den = 0.f;
#pragma unroll
    for (int f = 0; f < NBF; ++f) {
      float kpf = kp_s[l * NBF + f];
      S[f]  += kpf * vv;
      kc[f] += kpf;
      float qpf = qp_s[l * NBF + f];
      num += qpf * S[f];
      den += qpf * kc[f];
    }
    oB[(size_t)l * DMODEL] = f2bf(num / (den + EPSF));
  }
}

// ---------------- host launch ----------------
extern "C" void kernel_launch(void* const* d_in, const int* in_sizes, int n_in,
                              void* d_out, int out_size, void* d_ws, size_t ws_size,
                              hipStream_t stream) {
  const float* q   = (const float*)d_in[0];
  const float* k   = (const float*)d_in[1];
  const float* v   = (const float*)d_in[2];
  const float* w_q = (const float*)d_in[3];
  const float* w_k = (const float*)d_in[4];
  const float* w_v = (const float*)d_in[5];
  const float* w_o = (const float*)d_in[6];
  const float* omega = (const float*)d_in[7];
  float* out = (float*)d_out;

  constexpr size_t NQ = (size_t)BATCH * L_SEQ * DMODEL;      // 8388608
  constexpr size_t NW = (size_t)DMODEL * DMODEL;             // 1048576
  constexpr size_t NWT = (size_t)HEADS * NBF * DMODEL;       // 262144
  constexpr size_t NP = (size_t)BATCH * HEADS * L_SEQ * NBF; // 2097152
  constexpr size_t NS = (size_t)NCHAIN * NCHUNK * STATE_SZ;

  char* ws = (char*)d_ws;
  size_t off = 0;
  auto alc = [&](size_t bytes) { void* p = ws + off; off += (bytes + 255) & ~(size_t)255; return p; };
  unsigned short* wvb = (unsigned short*)alc(NW * 2);
  unsigned short* wob = (unsigned short*)alc(NW * 2);
  unsigned short* wtq = (unsigned short*)alc(NWT * 2);
  unsigned short* wtk = (unsigned short*)alc(NWT * 2);
  unsigned short* vh  = (unsigned short*)alc(NQ * 2);
  unsigned short* attn = (unsigned short*)alc(NQ * 2);
  float* qp  = (float*)alc(NP * 4);
  float* kp  = (float*)alc(NP * 4);
  float* Sws = (float*)alc(NS * 4);

  prep<<<2560, 256, 0, stream>>>(w_v, w_o, w_q, w_k, omega, wvb, wob, wtq, wtk);
  proj_all<<<768, 256, 0, stream>>>(q, k, v, wtq, wtk, wvb, qp, kp, vh);

  scan_chunk_sum<<<NCHAIN * NCHUNK, 64, 0, stream>>>(kp, vh, Sws);
  scan_chunks<<<dim3(NCHAIN, (STATE_SZ + 63) / 64), 64, 0, stream>>>(Sws);
  scan_apply<<<NCHAIN * NCHUNK, 64, 0, stream>>>(qp, kp, vh, Sws, attn);

  gemm_o<<<512, 256, 0, stream>>>(attn, wob, out);
}

// Round 6
// 167.521 us; speedup vs baseline: 1.1077x; 1.0123x over previous
//
#include <hip/hip_runtime.h>

#define L_SEQ   4096
#define BATCH   2
#define DMODEL  1024
#define HEADS   16
#define DKH     64
#define NBF     16
#define CHUNK   64
#define NCHUNK  64          // L_SEQ / CHUNK
#define NCHAIN  32          // BATCH * HEADS
#define STATE_SZ 1040       // NBF*DKH + NBF
#define EPSF    1e-6f

typedef __attribute__((ext_vector_type(8))) __bf16 bf16x8;
typedef __attribute__((ext_vector_type(4))) float  floatx4;

__device__ __forceinline__ unsigned short f2bf(float x) {
  unsigned u = __builtin_bit_cast(unsigned, x);
  u += 0x7fffu + ((u >> 16) & 1u);
  return (unsigned short)(u >> 16);
}
__device__ __forceinline__ float bf2f(unsigned short u) {
  return __builtin_bit_cast(float, ((unsigned)u) << 16);
}

#define GLOAD16(gp, lp) \
  __builtin_amdgcn_global_load_lds((const __attribute__((address_space(1))) void*)(gp), \
                                   (__attribute__((address_space(3))) void*)(lp), 16, 0, 0)

// ---------------- prep: cast wv,wo to bf16 + combine wtq,wtk ----------------
// blocks 0..2047: casts; 2048..2559: combine (z,h,s)
__global__ __launch_bounds__(256) void prep(const float* __restrict__ wv, const float* __restrict__ wo,
                                            const float* __restrict__ wq, const float* __restrict__ wk,
                                            const float* __restrict__ omega,
                                            unsigned short* __restrict__ wvb, unsigned short* __restrict__ wob,
                                            unsigned short* __restrict__ wtq, unsigned short* __restrict__ wtk) {
  __shared__ float ws[64 * 64];
  __shared__ float oms[NBF * 64];
  const int blk = blockIdx.x;
  const int tid = threadIdx.x;
  if (blk < 2048) {
    const float* in = (blk < 1024) ? wv : wo;
    unsigned short* out = (blk < 1024) ? wvb : wob;
    int i = (blk & 1023) * 256 + tid;
    float4 v4 = ((const float4*)in)[i];
    ushort4 o;
    o.x = f2bf(v4.x); o.y = f2bf(v4.y); o.z = f2bf(v4.z); o.w = f2bf(v4.w);
    ((ushort4*)out)[i] = o;
    return;
  }
  const int local = blk - 2048;          // 0..511
  const int z = local >> 8;              // 0:q 1:k
  const int h = (local & 255) >> 4;
  const int s = local & 15;              // 64-col slab
  const float* w = z ? wk : wq;
  unsigned short* wt = z ? wtk : wtq;
  for (int i = tid; i < 64 * 64; i += 256) {
    int r = i >> 6, c = i & 63;
    ws[i] = w[(size_t)(h * 64 + r) * DMODEL + s * 64 + c];
  }
  for (int i = tid; i < NBF * 64; i += 256) oms[i] = omega[i];
  __syncthreads();
  for (int j = tid; j < NBF * 64; j += 256) {
    int f = j >> 6, c = j & 63;
    float acc = 0.f;
#pragma unroll
    for (int d = 0; d < 64; ++d) acc += oms[f * 64 + d] * ws[d * 64 + c];
    wt[(size_t)(h * NBF + f) * DMODEL + s * 64 + c] = f2bf(acc);
  }
}

// ---------------- fused projections: q-feat | k-feat | v ----------------
// A is f32, staged via global_load_lds into slot-swizzled LDS; cvt->bf16 after ds_read.
// Plain single-buffered 2-barrier m97 loop, fully compiler-scheduled.
__global__ __launch_bounds__(256) void proj_all(const float* __restrict__ q, const float* __restrict__ k,
                                                const float* __restrict__ v,
                                                const unsigned short* __restrict__ wtq,
                                                const unsigned short* __restrict__ wtk,
                                                const unsigned short* __restrict__ wvb,
                                                float* __restrict__ qp_t, float* __restrict__ kp_t,
                                                unsigned short* __restrict__ vh) {
  constexpr int K = DMODEL;
  __shared__ char smem[24576];
  float* As = (float*)smem;                               // [128][32] f32, slot^(row&7)
  unsigned short* Bs = (unsigned short*)(smem + 16384);   // [128][32] bf16, slot^((row>>1)&3)

  const int tid  = threadIdx.x;
  const int wave = tid >> 6, lane = tid & 63;

  const int bid = blockIdx.x;
  const int id = (bid & 7) * 96 + (bid >> 3);   // bijective XCD swizzle (768 = 8*96)
  int op, mt, nt;
  const float* A;
  const unsigned short* Bt;
  if (id < 256) {            // q/k projection, N=256
    op = id >> 7;            // 0:q 1:k
    const int local = id & 127;
    nt = (local & 1) << 7;
    mt = (local >> 1) << 7;
    A  = op ? k : q;
    Bt = op ? wtk : wtq;
  } else {                   // v projection, N=1024
    op = 2;
    const int local = id - 256;
    nt = (local & 7) << 7;
    mt = (local >> 3) << 7;
    A  = v;
    Bt = wvb;
  }

  const int wm = (wave >> 1) << 6, wn = (wave & 1) << 6;
  const int r16 = lane & 15, kg = lane >> 4;

  floatx4 acc[4][4];
#pragma unroll
  for (int m = 0; m < 4; ++m)
#pragma unroll
    for (int n = 0; n < 4; ++n) acc[m][n] = floatx4{0.f, 0.f, 0.f, 0.f};

  // A staging: 16 x 1KB insts (4/wave). dest row = wave*32 + j*8 + (lane>>3), slot = lane&7.
  // source col pre-swizzled: (lane&7) ^ (lane>>3)  [= slot ^ (row&7)]
  const int arow = wave * 32 + (lane >> 3);
  const int acolsw = ((lane & 7) ^ (lane >> 3)) << 2;
  const float* aG = A + (size_t)(mt + arow) * K + acolsw;
  // B staging: 8 x 1KB insts (2/wave). dest row = wave*16 + (lane>>2) (+64), slot = lane&3.
  // source col pre-swizzled: ((lane&3) ^ ((lane>>3)&3)) * 8 bf16
  const int brow = wave * 16 + (lane >> 2);
  const int bcolsw = (((lane & 3) ^ ((lane >> 3) & 3)) << 3);
  const unsigned short* bG = Bt + (size_t)(nt + brow) * K + bcolsw;

  for (int kt = 0; kt < K; kt += 32) {
#pragma unroll
    for (int j = 0; j < 4; ++j)
      GLOAD16(aG + (size_t)(8 * j) * K + kt, smem + wave * 4096 + j * 1024);
    GLOAD16(bG + kt, (char*)Bs + wave * 1024);
    GLOAD16(bG + (size_t)64 * K + kt, (char*)Bs + 4096 + wave * 1024);
    __syncthreads();

    bf16x8 af[4], bfr[4];
#pragma unroll
    for (int m = 0; m < 4; ++m) {
      const int row = wm + m * 16 + r16;
      const int sA = (kg << 1) ^ (r16 & 7);
      floatx4 lo = *(const floatx4*)(smem + row * 128 + sA * 16);
      floatx4 hi = *(const floatx4*)(smem + row * 128 + (sA ^ 1) * 16);
#pragma unroll
      for (int t2 = 0; t2 < 4; ++t2) {
        af[m][t2]     = (__bf16)lo[t2];
        af[m][4 + t2] = (__bf16)hi[t2];
      }
    }
#pragma unroll
    for (int n = 0; n < 4; ++n) {
      const int row = wn + n * 16 + r16;
      const int sB = kg ^ ((r16 >> 1) & 3);
      bfr[n] = *(const bf16x8*)((char*)Bs + row * 64 + sB * 16);
    }
#pragma unroll
    for (int m = 0; m < 4; ++m)
#pragma unroll
      for (int n = 0; n < 4; ++n)
        acc[m][n] = __builtin_amdgcn_mfma_f32_16x16x32_bf16(af[m], bfr[n], acc[m][n], 0, 0, 0);
    __syncthreads();
  }

  if (op < 2) {
    // feature epilogue: 16 features of one (row, head) live in lanes r16=0..15
    float* xp_t = op ? kp_t : qp_t;
    const int hbase = (nt + wn) >> 4;
#pragma unroll
    for (int m = 0; m < 4; ++m) {
#pragma unroll
      for (int n = 0; n < 4; ++n) {
        const int hglob = hbase + n;
#pragma unroll
        for (int r = 0; r < 4; ++r) {
          float x = acc[m][n][r];
          float p = __expf(-0.5f * x * x);
          float s = p;
          s += __shfl_xor(s, 1);
          s += __shfl_xor(s, 2);
          s += __shfl_xor(s, 4);
          s += __shfl_xor(s, 8);
          float o = p / (s + EPSF);
          const int row = mt + wm + m * 16 + kg * 4 + r;
          const int b = row >> 12, l = row & 4095;
          xp_t[(((size_t)(b * HEADS + hglob)) * L_SEQ + l) * NBF + r16] = o;
        }
      }
    }
  } else {
#pragma unroll
    for (int m = 0; m < 4; ++m) {
      const int row0 = mt + wm + m * 16 + kg * 4;
#pragma unroll
      for (int n = 0; n < 4; ++n) {
        const int col = nt + wn + n * 16 + r16;
#pragma unroll
        for (int r = 0; r < 4; ++r)
          vh[(size_t)(row0 + r) * DMODEL + col] = f2bf(acc[m][n][r]);
      }
    }
  }
}

// ---------------- o-GEMM: out(f32) = attn(bf16) * wob^T; plain loop + slot swizzle ----------------
__global__ __launch_bounds__(256) void gemm_o(const unsigned short* __restrict__ A,
                                              const unsigned short* __restrict__ Bt,
                                              float* __restrict__ C) {
  constexpr int K = DMODEL;
  __shared__ unsigned short As[128 * 32];
  __shared__ unsigned short Bs[128 * 32];
  const int tid  = threadIdx.x;
  const int wave = tid >> 6, lane = tid & 63;
  const int bid = blockIdx.x;
  const int id = (bid & 7) * 64 + (bid >> 3);   // bijective XCD swizzle (512 = 8*64)
  const int nt = (id & 7) << 7, mt = (id >> 3) << 7;
  const int wm = (wave >> 1) << 6, wn = (wave & 1) << 6;
  const int r16 = lane & 15, kg = lane >> 4;

  floatx4 acc[4][4];
#pragma unroll
  for (int m = 0; m < 4; ++m)
#pragma unroll
    for (int n = 0; n < 4; ++n) acc[m][n] = floatx4{0.f, 0.f, 0.f, 0.f};

  const int ldrow = wave * 16 + (lane >> 2);
  const int ldcolsw = (((lane & 3) ^ ((lane >> 3) & 3)) << 3);
  const unsigned short* aG = A  + (size_t)(mt + ldrow) * K + ldcolsw;
  const unsigned short* bG = Bt + (size_t)(nt + ldrow) * K + ldcolsw;

  for (int kt = 0; kt < K; kt += 32) {
    GLOAD16(aG + kt, (char*)As + wave * 1024);
    GLOAD16(aG + (size_t)64 * K + kt, (char*)As + 4096 + wave * 1024);
    GLOAD16(bG + kt, (char*)Bs + wave * 1024);
    GLOAD16(bG + (size_t)64 * K + kt, (char*)Bs + 4096 + wave * 1024);
    __syncthreads();

    bf16x8 af[4], bfr[4];
#pragma unroll
    for (int m = 0; m < 4; ++m) {
      const int row = wm + m * 16 + r16;
      const int sA = kg ^ ((r16 >> 1) & 3);
      af[m] = *(const bf16x8*)((char*)As + row * 64 + sA * 16);
    }
#pragma unroll
    for (int n = 0; n < 4; ++n) {
      const int row = wn + n * 16 + r16;
      const int sB = kg ^ ((r16 >> 1) & 3);
      bfr[n] = *(const bf16x8*)((char*)Bs + row * 64 + sB * 16);
    }
#pragma unroll
    for (int m = 0; m < 4; ++m)
#pragma unroll
      for (int n = 0; n < 4; ++n)
        acc[m][n] = __builtin_amdgcn_mfma_f32_16x16x32_bf16(af[m], bfr[n], acc[m][n], 0, 0, 0);
    __syncthreads();
  }

#pragma unroll
  for (int m = 0; m < 4; ++m) {
    const int row0 = mt + wm + m * 16 + kg * 4;
#pragma unroll
    for (int n = 0; n < 4; ++n) {
      const int col = nt + wn + n * 16 + r16;
#pragma unroll
      for (int r = 0; r < 4; ++r)
        C[(size_t)(row0 + r) * DMODEL + col] = acc[m][n][r];
    }
  }
}

// ---------------- scan phase A: per-chunk local sums ----------------
__global__ __launch_bounds__(64) void scan_chunk_sum(const float* __restrict__ kp_t,
                                                     const unsigned short* __restrict__ vh,
                                                     float* __restrict__ Sws) {
  const int c = blockIdx.x & (NCHUNK - 1);
  const int chain = blockIdx.x >> 6;
  const int b = chain >> 4, h = chain & 15;
  const int d = threadIdx.x;
  __shared__ float kp_s[CHUNK * NBF];
  const float* kpB = kp_t + ((size_t)chain * L_SEQ + c * CHUNK) * NBF;
  for (int i = 0; i < 16; ++i) kp_s[d + i * 64] = kpB[d + i * 64];
  __syncthreads();
  float S[NBF];
#pragma unroll
  for (int f = 0; f < NBF; ++f) S[f] = 0.f;
  const unsigned short* vB = vh + ((size_t)(b * L_SEQ + c * CHUNK)) * DMODEL + h * DKH + d;
  for (int l = 0; l < CHUNK; ++l) {
    float vv = bf2f(vB[(size_t)l * DMODEL]);
#pragma unroll
    for (int f = 0; f < NBF; ++f) S[f] += kp_s[l * NBF + f] * vv;
  }
  float* out = Sws + ((size_t)chain * NCHUNK + c) * STATE_SZ;
#pragma unroll
  for (int f = 0; f < NBF; ++f) out[f * 64 + d] = S[f];
  if (d < NBF) {
    float ks = 0.f;
    for (int l = 0; l < CHUNK; ++l) ks += kp_s[l * NBF + d];
    out[1024 + d] = ks;
  }
}

// ---------------- scan phase B: exclusive scan over chunks (parallel over e) ----------------
__global__ __launch_bounds__(64) void scan_chunks(float* __restrict__ Sws) {
  const int chain = blockIdx.x;
  const int e = blockIdx.y * 64 + threadIdx.x;
  if (e >= STATE_SZ) return;
  float acc = 0.f;
  float* p = Sws + (size_t)chain * NCHUNK * STATE_SZ + e;
  for (int c = 0; c < NCHUNK; ++c) {
    float v = p[(size_t)c * STATE_SZ];
    p[(size_t)c * STATE_SZ] = acc;
    acc += v;
  }
}

// ---------------- scan phase C: apply within chunk, write attn (bf16) ----------------
__global__ __launch_bounds__(64) void scan_apply(const float* __restrict__ qp_t,
                                                 const float* __restrict__ kp_t,
                                                 const unsigned short* __restrict__ vh,
                                                 const float* __restrict__ Sws,
                                                 unsigned short* __restrict__ attn) {
  const int c = blockIdx.x & (NCHUNK - 1);
  const int chain = blockIdx.x >> 6;
  const int b = chain >> 4, h = chain & 15;
  const int d = threadIdx.x;
  __shared__ float kp_s[CHUNK * NBF];
  __shared__ float qp_s[CHUNK * NBF];
  {
    const float* kpB = kp_t + ((size_t)chain * L_SEQ + c * CHUNK) * NBF;
    const float* qpB = qp_t + ((size_t)chain * L_SEQ + c * CHUNK) * NBF;
    for (int i = 0; i < 16; ++i) {
      kp_s[d + i * 64] = kpB[d + i * 64];
      qp_s[d + i * 64] = qpB[d + i * 64];
    }
  }
  __syncthreads();
  const float* st = Sws + ((size_t)chain * NCHUNK + c) * STATE_SZ;
  float S[NBF], kc[NBF];
#pragma unroll
  for (int f = 0; f < NBF; ++f) S[f] = st[f * 64 + d];
#pragma unroll
  for (int f = 0; f < NBF; ++f) kc[f] = st[1024 + f];
  const unsigned short* vB = vh + ((size_t)(b * L_SEQ + c * CHUNK)) * DMODEL + h * DKH + d;
  unsigned short* oB = attn + ((size_t)(b * L_SEQ + c * CHUNK)) * DMODEL + h * DKH + d;
  for (int l = 0; l < CHUNK; ++l) {
    float vv = bf2f(vB[(size_t)l * DMODEL]);
    float num = 0.f, den = 0.f;
#pragma unroll
    for (int f = 0; f < NBF; ++f) {
      float kpf = kp_s[l * NBF + f];
      S[f]  += kpf * vv;
      kc[f] += kpf;
      float qpf = qp_s[l * NBF + f];
      num += qpf * S[f];
      den += qpf * kc[f];
    }
    oB[(size_t)l * DMODEL] = f2bf(num / (den + EPSF));
  }
}

// ---------------- host launch ----------------
extern "C" void kernel_launch(void* const* d_in, const int* in_sizes, int n_in,
                              void* d_out, int out_size, void* d_ws, size_t ws_size,
                              hipStream_t stream) {
  const float* q   = (const float*)d_in[0];
  const float* k   = (const float*)d_in[1];
  const float* v   = (const float*)d_in[2];
  const float* w_q = (const float*)d_in[3];
  const float* w_k = (const float*)d_in[4];
  const float* w_v = (const float*)d_in[5];
  const float* w_o = (const float*)d_in[6];
  const float* omega = (const float*)d_in[7];
  float* out = (float*)d_out;

  constexpr size_t NQ = (size_t)BATCH * L_SEQ * DMODEL;      // 8388608
  constexpr size_t NW = (size_t)DMODEL * DMODEL;             // 1048576
  constexpr size_t NWT = (size_t)HEADS * NBF * DMODEL;       // 262144
  constexpr size_t NP = (size_t)BATCH * HEADS * L_SEQ * NBF; // 2097152
  constexpr size_t NS = (size_t)NCHAIN * NCHUNK * STATE_SZ;

  char* ws = (char*)d_ws;
  size_t off = 0;
  auto alc = [&](size_t bytes) { void* p = ws + off; off += (bytes + 255) & ~(size_t)255; return p; };
  unsigned short* wvb = (unsigned short*)alc(NW * 2);
  unsigned short* wob = (unsigned short*)alc(NW * 2);
  unsigned short* wtq = (unsigned short*)alc(NWT * 2);
  unsigned short* wtk = (unsigned short*)alc(NWT * 2);
  unsigned short* vh  = (unsigned short*)alc(NQ * 2);
  unsigned short* attn = (unsigned short*)alc(NQ * 2);
  float* qp  = (float*)alc(NP * 4);
  float* kp  = (float*)alc(NP * 4);
  float* Sws = (float*)alc(NS * 4);

  prep<<<2560, 256, 0, stream>>>(w_v, w_o, w_q, w_k, omega, wvb, wob, wtq, wtk);
  proj_all<<<768, 256, 0, stream>>>(q, k, v, wtq, wtk, wvb, qp, kp, vh);

  scan_chunk_sum<<<NCHAIN * NCHUNK, 64, 0, stream>>>(kp, vh, Sws);
  scan_chunks<<<dim3(NCHAIN, (STATE_SZ + 63) / 64), 64, 0, stream>>>(Sws);
  scan_apply<<<NCHAIN * NCHUNK, 64, 0, stream>>>(qp, kp, vh, Sws, attn);

  gemm_o<<<512, 256, 0, stream>>>(attn, wob, out);
}

// Round 8
// 145.082 us; speedup vs baseline: 1.2791x; 1.1547x over previous
//
#include <hip/hip_runtime.h>

#define L_SEQ   4096
#define BATCH   2
#define DMODEL  1024
#define HEADS   16
#define DKH     64
#define NBF     16
#define CHUNK   64
#define NCHUNK  64          // L_SEQ / CHUNK
#define NCHAIN  32          // BATCH * HEADS
#define STATE_SZ 1040       // NBF*DKH + NBF
#define EPSF    1e-6f

typedef __attribute__((ext_vector_type(8))) __bf16 bf16x8;
typedef __attribute__((ext_vector_type(4))) float  floatx4;

__device__ __forceinline__ unsigned short f2bf(float x) {
  unsigned u = __builtin_bit_cast(unsigned, x);
  u += 0x7fffu + ((u >> 16) & 1u);
  return (unsigned short)(u >> 16);
}
__device__ __forceinline__ float bf2f(unsigned short u) {
  return __builtin_bit_cast(float, ((unsigned)u) << 16);
}

#define GLOAD16(gp, lp) \
  __builtin_amdgcn_global_load_lds((const __attribute__((address_space(1))) void*)(gp), \
                                   (__attribute__((address_space(3))) void*)(lp), 16, 0, 0)

// ---------------- prep: cast wv,wo to bf16 + combine wtq,wtk ----------------
__global__ __launch_bounds__(256) void prep(const float* __restrict__ wv, const float* __restrict__ wo,
                                            const float* __restrict__ wq, const float* __restrict__ wk,
                                            const float* __restrict__ omega,
                                            unsigned short* __restrict__ wvb, unsigned short* __restrict__ wob,
                                            unsigned short* __restrict__ wtq, unsigned short* __restrict__ wtk) {
  __shared__ float ws[64 * 64];
  __shared__ float oms[NBF * 64];
  const int blk = blockIdx.x;
  const int tid = threadIdx.x;
  if (blk < 2048) {
    const float* in = (blk < 1024) ? wv : wo;
    unsigned short* out = (blk < 1024) ? wvb : wob;
    int i = (blk & 1023) * 256 + tid;
    float4 v4 = ((const float4*)in)[i];
    ushort4 o;
    o.x = f2bf(v4.x); o.y = f2bf(v4.y); o.z = f2bf(v4.z); o.w = f2bf(v4.w);
    ((ushort4*)out)[i] = o;
    return;
  }
  const int local = blk - 2048;          // 0..511
  const int z = local >> 8;              // 0:q 1:k
  const int h = (local & 255) >> 4;
  const int s = local & 15;              // 64-col slab
  const float* w = z ? wk : wq;
  unsigned short* wt = z ? wtk : wtq;
  for (int i = tid; i < 64 * 64; i += 256) {
    int r = i >> 6, c = i & 63;
    ws[i] = w[(size_t)(h * 64 + r) * DMODEL + s * 64 + c];
  }
  for (int i = tid; i < NBF * 64; i += 256) oms[i] = omega[i];
  __syncthreads();
  for (int j = tid; j < NBF * 64; j += 256) {
    int f = j >> 6, c = j & 63;
    float acc = 0.f;
#pragma unroll
    for (int d = 0; d < 64; ++d) acc += oms[f * 64 + d] * ws[d * 64 + c];
    wt[(size_t)(h * NBF + f) * DMODEL + s * 64 + c] = f2bf(acc);
  }
}

// ---------------- fused projections: q-feat | k-feat | v ----------------
// f32 A staged via global_load_lds (slot-swizzled), 2-phase double-buffered:
// stage(t+1) issued BEFORE compute(t); single __syncthreads per K-step drains it.
__global__ __launch_bounds__(256) void proj_all(const float* __restrict__ q, const float* __restrict__ k,
                                                const float* __restrict__ v,
                                                const unsigned short* __restrict__ wtq,
                                                const unsigned short* __restrict__ wtk,
                                                const unsigned short* __restrict__ wvb,
                                                float* __restrict__ qp_t, float* __restrict__ kp_t,
                                                unsigned short* __restrict__ vh) {
  constexpr int K = DMODEL, NT = K / 32;
  __shared__ char smem[2][24576];   // per buf: A f32 [128][32] = 16KB @0, B bf16 [128][32] = 8KB @16384

  const int tid  = threadIdx.x;
  const int wave = tid >> 6, lane = tid & 63;

  // XCD swizzle + qk/v interleave: every 3 consecutive ids on an XCD = {v, v, qk}
  const int bid = blockIdx.x;
  const int id = (bid & 7) * 96 + (bid >> 3);   // bijective (768 = 8*96)
  const int g = id / 3, r3 = id - g * 3;
  int op, mt, nt;
  const float* A;
  const unsigned short* Bt;
  if (r3 == 2) {             // qk tile g: 0..255
    op = g & 1;              // alternate q/k
    const int local = g >> 1;            // 0..127
    nt = (local & 1) << 7;
    mt = (local >> 1) << 7;
    A  = op ? k : q;
    Bt = op ? wtk : wtq;
  } else {                   // v tile vt: 0..511
    op = 2;
    const int vt = g * 2 + r3;
    nt = (vt & 7) << 7;
    mt = (vt >> 3) << 7;
    A  = v;
    Bt = wvb;
  }

  const int wm = (wave >> 1) << 6, wn = (wave & 1) << 6;
  const int r16 = lane & 15, kg = lane >> 4;

  floatx4 acc[4][4];
#pragma unroll
  for (int m = 0; m < 4; ++m)
#pragma unroll
    for (int n = 0; n < 4; ++n) acc[m][n] = floatx4{0.f, 0.f, 0.f, 0.f};

  // A staging: dest row = wave*32 + (lane>>3) + 8j, physical slot = lane&7 (16B f32 slots, 8/row)
  // source col pre-swizzled: slot ^ (row&7), row&7 == lane>>3
  const int arow = wave * 32 + (lane >> 3);
  const int acolsw = ((lane & 7) ^ (lane >> 3)) << 2;
  const float* aG = A + (size_t)(mt + arow) * K + acolsw;
  // B staging: dest row = wave*16 + (lane>>2) (+64), physical slot = lane&3 (16B bf16 slots, 4/row)
  // source col pre-swizzled: (slot ^ ((row>>1)&3)) * 8 bf16
  const int brow = wave * 16 + (lane >> 2);
  const int bcolsw = (((lane & 3) ^ ((lane >> 3) & 3)) << 3);
  const unsigned short* bG = Bt + (size_t)(nt + brow) * K + bcolsw;

  auto stage = [&](int buf, int kt) {
    char* base = smem[buf];
#pragma unroll
    for (int j = 0; j < 4; ++j)
      GLOAD16(aG + (size_t)(8 * j) * K + kt, base + wave * 4096 + j * 1024);
    GLOAD16(bG + kt, base + 16384 + wave * 1024);
    GLOAD16(bG + (size_t)64 * K + kt, base + 16384 + 4096 + wave * 1024);
  };
  auto compute = [&](int buf) {
    const char* base = smem[buf];
    bf16x8 af[4], bfr[4];
#pragma unroll
    for (int m = 0; m < 4; ++m) {
      const int row = wm + m * 16 + r16;
      const int sA = (kg << 1) ^ (r16 & 7);
      floatx4 lo = *(const floatx4*)(base + row * 128 + sA * 16);
      floatx4 hi = *(const floatx4*)(base + row * 128 + (sA ^ 1) * 16);
#pragma unroll
      for (int t2 = 0; t2 < 4; ++t2) {
        af[m][t2]     = (__bf16)lo[t2];
        af[m][4 + t2] = (__bf16)hi[t2];
      }
    }
#pragma unroll
    for (int n = 0; n < 4; ++n) {
      const int row = wn + n * 16 + r16;
      const int sB = kg ^ ((r16 >> 1) & 3);
      bfr[n] = *(const bf16x8*)(base + 16384 + row * 64 + sB * 16);
    }
#pragma unroll
    for (int m = 0; m < 4; ++m)
#pragma unroll
      for (int n = 0; n < 4; ++n)
        acc[m][n] = __builtin_amdgcn_mfma_f32_16x16x32_bf16(af[m], bfr[n], acc[m][n], 0, 0, 0);
  };

  stage(0, 0);
  __syncthreads();
  for (int t = 0; t < NT; ++t) {
    if (t + 1 < NT) stage((t + 1) & 1, (t + 1) * 32);  // prefetch flies under compute
    compute(t & 1);
    __syncthreads();                                    // implicit vmcnt(0)+lgkmcnt(0)
  }

  if (op < 2) {
    float* xp_t = op ? kp_t : qp_t;
    const int hbase = (nt + wn) >> 4;
#pragma unroll
    for (int m = 0; m < 4; ++m) {
#pragma unroll
      for (int n = 0; n < 4; ++n) {
        const int hglob = hbase + n;
#pragma unroll
        for (int r = 0; r < 4; ++r) {
          float x = acc[m][n][r];
          float p = __expf(-0.5f * x * x);
          float s = p;
          s += __shfl_xor(s, 1);
          s += __shfl_xor(s, 2);
          s += __shfl_xor(s, 4);
          s += __shfl_xor(s, 8);
          float o = p / (s + EPSF);
          const int row = mt + wm + m * 16 + kg * 4 + r;
          const int b = row >> 12, l = row & 4095;
          xp_t[(((size_t)(b * HEADS + hglob)) * L_SEQ + l) * NBF + r16] = o;
        }
      }
    }
  } else {
#pragma unroll
    for (int m = 0; m < 4; ++m) {
      const int row0 = mt + wm + m * 16 + kg * 4;
#pragma unroll
      for (int n = 0; n < 4; ++n) {
        const int col = nt + wn + n * 16 + r16;
#pragma unroll
        for (int r = 0; r < 4; ++r)
          vh[(size_t)(row0 + r) * DMODEL + col] = f2bf(acc[m][n][r]);
      }
    }
  }
}

// ---------------- o-GEMM: out(f32) = attn(bf16) * wob^T; 2-phase double-buffered ----------------
__global__ __launch_bounds__(256) void gemm_o(const unsigned short* __restrict__ A,
                                              const unsigned short* __restrict__ Bt,
                                              float* __restrict__ C) {
  constexpr int K = DMODEL, NT = K / 32;
  __shared__ char smem[2][16384];   // per buf: A bf16 8KB @0, B bf16 8KB @8192
  const int tid  = threadIdx.x;
  const int wave = tid >> 6, lane = tid & 63;
  const int bid = blockIdx.x;
  const int id = (bid & 7) * 64 + (bid >> 3);   // bijective XCD swizzle (512 = 8*64)
  const int nt = (id & 7) << 7, mt = (id >> 3) << 7;
  const int wm = (wave >> 1) << 6, wn = (wave & 1) << 6;
  const int r16 = lane & 15, kg = lane >> 4;

  floatx4 acc[4][4];
#pragma unroll
  for (int m = 0; m < 4; ++m)
#pragma unroll
    for (int n = 0; n < 4; ++n) acc[m][n] = floatx4{0.f, 0.f, 0.f, 0.f};

  const int ldrow = wave * 16 + (lane >> 2);
  const int ldcolsw = (((lane & 3) ^ ((lane >> 3) & 3)) << 3);
  const unsigned short* aG = A  + (size_t)(mt + ldrow) * K + ldcolsw;
  const unsigned short* bG = Bt + (size_t)(nt + ldrow) * K + ldcolsw;

  auto stage = [&](int buf, int kt) {
    char* base = smem[buf];
    GLOAD16(aG + kt, base + wave * 1024);
    GLOAD16(aG + (size_t)64 * K + kt, base + 4096 + wave * 1024);
    GLOAD16(bG + kt, base + 8192 + wave * 1024);
    GLOAD16(bG + (size_t)64 * K + kt, base + 8192 + 4096 + wave * 1024);
  };
  auto compute = [&](int buf) {
    const char* base = smem[buf];
    bf16x8 af[4], bfr[4];
#pragma unroll
    for (int m = 0; m < 4; ++m) {
      const int row = wm + m * 16 + r16;
      const int sA = kg ^ ((r16 >> 1) & 3);
      af[m] = *(const bf16x8*)(base + row * 64 + sA * 16);
    }
#pragma unroll
    for (int n = 0; n < 4; ++n) {
      const int row = wn + n * 16 + r16;
      const int sB = kg ^ ((r16 >> 1) & 3);
      bfr[n] = *(const bf16x8*)(base + 8192 + row * 64 + sB * 16);
    }
#pragma unroll
    for (int m = 0; m < 4; ++m)
#pragma unroll
      for (int n = 0; n < 4; ++n)
        acc[m][n] = __builtin_amdgcn_mfma_f32_16x16x32_bf16(af[m], bfr[n], acc[m][n], 0, 0, 0);
  };

  stage(0, 0);
  __syncthreads();
  for (int t = 0; t < NT; ++t) {
    if (t + 1 < NT) stage((t + 1) & 1, (t + 1) * 32);
    compute(t & 1);
    __syncthreads();
  }

#pragma unroll
  for (int m = 0; m < 4; ++m) {
    const int row0 = mt + wm + m * 16 + kg * 4;
#pragma unroll
    for (int n = 0; n < 4; ++n) {
      const int col = nt + wn + n * 16 + r16;
#pragma unroll
      for (int r = 0; r < 4; ++r)
        C[(size_t)(row0 + r) * DMODEL + col] = acc[m][n][r];
    }
  }
}

// ---------------- scan phase A: per-chunk local sums ----------------
__global__ __launch_bounds__(64) void scan_chunk_sum(const float* __restrict__ kp_t,
                                                     const unsigned short* __restrict__ vh,
                                                     float* __restrict__ Sws) {
  const int c = blockIdx.x & (NCHUNK - 1);
  const int chain = blockIdx.x >> 6;
  const int b = chain >> 4, h = chain & 15;
  const int d = threadIdx.x;
  __shared__ float kp_s[CHUNK * NBF];
  const float* kpB = kp_t + ((size_t)chain * L_SEQ + c * CHUNK) * NBF;
  for (int i = 0; i < 16; ++i) kp_s[d + i * 64] = kpB[d + i * 64];
  __syncthreads();
  float S[NBF];
#pragma unroll
  for (int f = 0; f < NBF; ++f) S[f] = 0.f;
  const unsigned short* vB = vh + ((size_t)(b * L_SEQ + c * CHUNK)) * DMODEL + h * DKH + d;
  for (int l = 0; l < CHUNK; ++l) {
    float vv = bf2f(vB[(size_t)l * DMODEL]);
#pragma unroll
    for (int f = 0; f < NBF; ++f) S[f] += kp_s[l * NBF + f] * vv;
  }
  float* out = Sws + ((size_t)chain * NCHUNK + c) * STATE_SZ;
#pragma unroll
  for (int f = 0; f < NBF; ++f) out[f * 64 + d] = S[f];
  if (d < NBF) {
    float ks = 0.f;
    for (int l = 0; l < CHUNK; ++l) ks += kp_s[l * NBF + d];
    out[1024 + d] = ks;
  }
}

// ---------------- scan phase B: exclusive scan over chunks (parallel over e) ----------------
__global__ __launch_bounds__(64) void scan_chunks(float* __restrict__ Sws) {
  const int chain = blockIdx.x;
  const int e = blockIdx.y * 64 + threadIdx.x;
  if (e >= STATE_SZ) return;
  float acc = 0.f;
  float* p = Sws + (size_t)chain * NCHUNK * STATE_SZ + e;
  for (int c = 0; c < NCHUNK; ++c) {
    float v = p[(size_t)c * STATE_SZ];
    p[(size_t)c * STATE_SZ] = acc;
    acc += v;
  }
}

// ---------------- scan phase C: apply within chunk, write attn (bf16) ----------------
__global__ __launch_bounds__(64) void scan_apply(const float* __restrict__ qp_t,
                                                 const float* __restrict__ kp_t,
                                                 const unsigned short* __restrict__ vh,
                                                 const float* __restrict__ Sws,
                                                 unsigned short* __restrict__ attn) {
  const int c = blockIdx.x & (NCHUNK - 1);
  const int chain = blockIdx.x >> 6;
  const int b = chain >> 4, h = chain & 15;
  const int d = threadIdx.x;
  __shared__ float kp_s[CHUNK * NBF];
  __shared__ float qp_s[CHUNK * NBF];
  {
    const float* kpB = kp_t + ((size_t)chain * L_SEQ + c * CHUNK) * NBF;
    const float* qpB = qp_t + ((size_t)chain * L_SEQ + c * CHUNK) * NBF;
    for (int i = 0; i < 16; ++i) {
      kp_s[d + i * 64] = kpB[d + i * 64];
      qp_s[d + i * 64] = qpB[d + i * 64];
    }
  }
  __syncthreads();
  const float* st = Sws + ((size_t)chain * NCHUNK + c) * STATE_SZ;
  float S[NBF], kc[NBF];
#pragma unroll
  for (int f = 0; f < NBF; ++f) S[f] = st[f * 64 + d];
#pragma unroll
  for (int f = 0; f < NBF; ++f) kc[f] = st[1024 + f];
  const unsigned short* vB = vh + ((size_t)(b * L_SEQ + c * CHUNK)) * DMODEL + h * DKH + d;
  unsigned short* oB = attn + ((size_t)(b * L_SEQ + c * CHUNK)) * DMODEL + h * DKH + d;
  for (int l = 0; l < CHUNK; ++l) {
    float vv = bf2f(vB[(size_t)l * DMODEL]);
    float num = 0.f, den = 0.f;
#pragma unroll
    for (int f = 0; f < NBF; ++f) {
      float kpf = kp_s[l * NBF + f];
      S[f]  += kpf * vv;
      kc[f] += kpf;
      float qpf = qp_s[l * NBF + f];
      num += qpf * S[f];
      den += qpf * kc[f];
    }
    oB[(size_t)l * DMODEL] = f2bf(num / (den + EPSF));
  }
}

// ---------------- host launch ----------------
extern "C" void kernel_launch(void* const* d_in, const int* in_sizes, int n_in,
                              void* d_out, int out_size, void* d_ws, size_t ws_size,
                              hipStream_t stream) {
  const float* q   = (const float*)d_in[0];
  const float* k   = (const float*)d_in[1];
  const float* v   = (const float*)d_in[2];
  const float* w_q = (const float*)d_in[3];
  const float* w_k = (const float*)d_in[4];
  const float* w_v = (const float*)d_in[5];
  const float* w_o = (const float*)d_in[6];
  const float* omega = (const float*)d_in[7];
  float* out = (float*)d_out;

  constexpr size_t NQ = (size_t)BATCH * L_SEQ * DMODEL;      // 8388608
  constexpr size_t NW = (size_t)DMODEL * DMODEL;             // 1048576
  constexpr size_t NWT = (size_t)HEADS * NBF * DMODEL;       // 262144
  constexpr size_t NP = (size_t)BATCH * HEADS * L_SEQ * NBF; // 2097152
  constexpr size_t NS = (size_t)NCHAIN * NCHUNK * STATE_SZ;

  char* ws = (char*)d_ws;
  size_t off = 0;
  auto alc = [&](size_t bytes) { void* p = ws + off; off += (bytes + 255) & ~(size_t)255; return p; };
  unsigned short* wvb = (unsigned short*)alc(NW * 2);
  unsigned short* wob = (unsigned short*)alc(NW * 2);
  unsigned short* wtq = (unsigned short*)alc(NWT * 2);
  unsigned short* wtk = (unsigned short*)alc(NWT * 2);
  unsigned short* vh  = (unsigned short*)alc(NQ * 2);
  unsigned short* attn = (unsigned short*)alc(NQ * 2);
  float* qp  = (float*)alc(NP * 4);
  float* kp  = (float*)alc(NP * 4);
  float* Sws = (float*)alc(NS * 4);

  prep<<<2560, 256, 0, stream>>>(w_v, w_o, w_q, w_k, omega, wvb, wob, wtq, wtk);
  proj_all<<<768, 256, 0, stream>>>(q, k, v, wtq, wtk, wvb, qp, kp, vh);

  scan_chunk_sum<<<NCHAIN * NCHUNK, 64, 0, stream>>>(kp, vh, Sws);
  scan_chunks<<<dim3(NCHAIN, (STATE_SZ + 63) / 64), 64, 0, stream>>>(Sws);
  scan_apply<<<NCHAIN * NCHUNK, 64, 0, stream>>>(qp, kp, vh, Sws, attn);

  gemm_o<<<512, 256, 0, stream>>>(attn, wob, out);
}